// Round 8
// baseline (52436.572 us; speedup 1.0000x reference)
//
#include <hip/hip_runtime.h>
#include <math.h>

#define BB 8
#define NN 2048
#define KK 20
#define OCH 2564
#define OCN ((size_t)OCH*NN)
#define EPSD 1e-5
#define SLOPED 0.2
#define TS 64

// ---------------- ws layout (float offsets) ----------------
// pd  (f32 NN*NN)        : 0 .. 4,194,304
// xA  (f32 B*128*N)      : 4,194,304 .. 6,291,456
// xB  (f32 B*128*N)      : 6,291,456 .. 8,388,608
// y5  (f32 B*1024*N)     : overlays [0 .. 16,777,216) (pd/xA/xB dead)
// idx (int B*N*K)        : 16,777,216 .. 17,104,896
// xx  (f32 B*N)          : 17,104,896 ..
// s1/s2/sc/sh doubles    : 17,137,664 ..
#define WS_PD   ((size_t)0)
#define WS_XA   ((size_t)4194304)
#define WS_XB   ((size_t)6291456)
#define WS_Y5   ((size_t)0)
#define WS_IDX  ((size_t)16777216)
#define WS_XX   ((size_t)17104896)
#define WS_S1   ((size_t)17137664)
#define WS_S2   (WS_S1 + 2048)
#define WS_SC   (WS_S2 + 2048)
#define WS_SH   (WS_SC + 2048)

static inline int cdiv(int a, int b){ return (a+b-1)/b; }

// out[b, 2048+c, n] = xyz[b,n,c] (f32) ; xA[(b*3+c)*NN+n] = xyz (f32)
__global__ void k_prep_x0(const float* __restrict__ xyz, float* __restrict__ out,
                          float* __restrict__ xA){
  int id = blockIdx.x*256 + threadIdx.x;
  if (id >= BB*NN) return;
  int b = id / NN, n = id % NN;
  const float* p = xyz + ((size_t)b*NN + n)*3;
  float* o = out + (size_t)b*OCN + (size_t)2048*NN + n;
  o[0] = p[0]; o[(size_t)NN] = p[1]; o[2*(size_t)NN] = p[2];
  float* xa = xA + (size_t)b*3*NN + n;
  xa[0] = p[0]; xa[(size_t)NN] = p[1]; xa[2*(size_t)NN] = p[2];
}

// xx[b][n] = sum_c x[c,n]^2 in f32, numpy-style: rounded squares;
// sequential for C<=8, 8-accumulator pairwise for C=64/128.
__global__ void k_xx32(const float* __restrict__ x, int C, float* __restrict__ xx){
  int b = blockIdx.y;
  int n = blockIdx.x*256 + threadIdx.x;
  const float* p = x + (size_t)b*C*NN + n;
  float a;
  if (C <= 8){
    a = 0.f;
    for (int c = 0; c < C; c++){ float v = p[(size_t)c*NN]; float s = v*v; a = a + s; }
  } else {
    float r0,r1,r2,r3,r4,r5,r6,r7;
    { float v;
      v = p[0];            r0 = v*v;
      v = p[(size_t)1*NN]; r1 = v*v;
      v = p[(size_t)2*NN]; r2 = v*v;
      v = p[(size_t)3*NN]; r3 = v*v;
      v = p[(size_t)4*NN]; r4 = v*v;
      v = p[(size_t)5*NN]; r5 = v*v;
      v = p[(size_t)6*NN]; r6 = v*v;
      v = p[(size_t)7*NN]; r7 = v*v;
    }
    for (int i = 8; i < C; i += 8){
      float v;
      v = p[(size_t)(i+0)*NN]; r0 = r0 + v*v;
      v = p[(size_t)(i+1)*NN]; r1 = r1 + v*v;
      v = p[(size_t)(i+2)*NN]; r2 = r2 + v*v;
      v = p[(size_t)(i+3)*NN]; r3 = r3 + v*v;
      v = p[(size_t)(i+4)*NN]; r4 = r4 + v*v;
      v = p[(size_t)(i+5)*NN]; r5 = r5 + v*v;
      v = p[(size_t)(i+6)*NN]; r6 = r6 + v*v;
      v = p[(size_t)(i+7)*NN]; r7 = r7 + v*v;
    }
    a = ((r0+r1)+(r2+r3)) + ((r4+r5)+(r6+r7));
  }
  xx[b*NN + n] = a;
}

// pd[n][m] = (2*dot - xx[n]) - xx[m], f32, dot = sequential-c fmaf chain
__global__ __launch_bounds__(256) void k_pd32(const float* __restrict__ x, int C, int b,
                     const float* __restrict__ xx, float* __restrict__ pd){
  __shared__ float As[8][TS];
  __shared__ float Bsh[8][TS];
  int n0 = blockIdx.y*TS, m0 = blockIdx.x*TS;
  int tid = threadIdx.x;
  int tx = tid % 16, ty = tid / 16;
  const float* xb = x + (size_t)b*C*NN;
  float acc[4][4] = {};
  for (int c0 = 0; c0 < C; c0 += 8){
    int r = tid / 64, col = tid % 64;
    #pragma unroll
    for (int rr = 0; rr < 2; rr++){
      int c = c0 + r + rr*4;
      float av = 0.f, bv = 0.f;
      if (c < C){ av = xb[(size_t)c*NN + n0 + col]; bv = xb[(size_t)c*NN + m0 + col]; }
      As[r+rr*4][col] = av; Bsh[r+rr*4][col] = bv;
    }
    __syncthreads();
    #pragma unroll
    for (int c = 0; c < 8; c++){          // zero-padded tail: fmaf(0,0,acc)==acc exactly
      float a[4], bbv[4];
      #pragma unroll
      for (int i=0;i<4;i++) a[i] = As[c][ty*4+i];
      #pragma unroll
      for (int j=0;j<4;j++) bbv[j] = Bsh[c][tx*4+j];
      #pragma unroll
      for (int i=0;i<4;i++)
        #pragma unroll
        for (int j=0;j<4;j++)
          acc[i][j] = fmaf(a[i], bbv[j], acc[i][j]);
    }
    __syncthreads();
  }
  const float* xxb = xx + b*NN;
  #pragma unroll
  for (int i=0;i<4;i++){
    int n = n0 + ty*4 + i;
    float xn = xxb[n];
    #pragma unroll
    for (int j=0;j<4;j++){
      int m = m0 + tx*4 + j;
      float t = 2.f*acc[i][j];            // exact (power of two)
      pd[(size_t)n*NN + m] = (t - xn) - xxb[m];
    }
  }
}

// serial top-20 per row (largest, ties -> lower index), f32
__global__ __launch_bounds__(64) void k_topk_simple(const float* __restrict__ pd, int b,
                                                    int* __restrict__ idx){
  int n = blockIdx.x*64 + threadIdx.x;
  if (n >= NN) return;
  const float* row = pd + (size_t)n*NN;
  float vals[KK]; int inds[KK];
  #pragma unroll
  for (int i=0;i<KK;i++){ vals[i] = -INFINITY; inds[i] = 0; }
  for (int m = 0; m < NN; m++){
    float v = row[m];
    if (v > vals[KK-1]){
      #pragma unroll
      for (int i=KK-1;i>0;--i){
        if (vals[i-1] < v){ vals[i]=vals[i-1]; inds[i]=inds[i-1]; }
      }
      bool done = false;
      #pragma unroll
      for (int i=0;i<KK;i++){
        bool pl = (!done) && (vals[i] < v);
        if (pl){ vals[i]=v; inds[i]=m; done=true; }
      }
    }
  }
  int* op = idx + ((size_t)b*NN + n)*KK;
  #pragma unroll
  for (int i=0;i<KK;i++) op[i] = inds[i];
}

// LITERAL edge-conv: f32 features in LDS, f64 math.
template<int OUT>
__global__ void k_edge(const float* __restrict__ x, const float* __restrict__ W,
                       const int* __restrict__ idx, int C, int O,
                       double* __restrict__ s1, double* __restrict__ s2,
                       const double* __restrict__ scale, const double* __restrict__ shift,
                       float* __restrict__ outF, float* __restrict__ xnext){
  int n = blockIdx.x, b = blockIdx.y;
  __shared__ int ids[KK];
  extern __shared__ float xs[];   // xs[0..C)=x_n ; xs[(k+1)*C + c]=x_{j_k}
  if (threadIdx.x < KK) ids[threadIdx.x] = idx[((size_t)b*NN + n)*KK + threadIdx.x];
  __syncthreads();
  const float* xb = x + (size_t)b*C*NN;
  int tot = (KK+1)*C;
  for (int t = threadIdx.x; t < tot; t += blockDim.x){
    int slot = t / C, c = t - slot*C;
    int col = (slot == 0) ? n : ids[slot-1];
    xs[t] = xb[(size_t)c*NN + col];
  }
  __syncthreads();
  int o = threadIdx.x;
  if (o >= O) return;
  const float* wr = W + (size_t)o*2*C;
  double cterm = 0.0;
  for (int c = 0; c < C; c++) cterm = fma((double)wr[C+c], (double)xs[c], cterm);
  double acc[KK];
  #pragma unroll
  for (int k=0;k<KK;k++) acc[k] = 0.0;
  for (int c = 0; c < C; c++){
    double wf = (double)wr[c];
    double xn = (double)xs[c];
    #pragma unroll
    for (int k=0;k<KK;k++) acc[k] = fma(wf, (double)xs[(k+1)*C + c] - xn, acc[k]);
  }
  if (!OUT){
    double s1p = 0.0, s2p = 0.0;
    #pragma unroll
    for (int k=0;k<KK;k++){ double y = acc[k] + cterm; s1p += y; s2p += y*y; }
    atomicAdd(&s1[o], s1p);
    atomicAdd(&s2[o], s2p);
  } else {
    double sc = scale[o], sh = shift[o];
    double zm = -INFINITY;
    #pragma unroll
    for (int k=0;k<KK;k++){
      double z = sc*(acc[k] + cterm) + sh;
      z = z > 0.0 ? z : SLOPED*z;
      zm = fmax(zm, z);
    }
    float zf = (float)zm;
    outF[(size_t)b*OCN + (size_t)o*NN + n] = zf;
    if (xnext) xnext[((size_t)b*O + o)*NN + n] = zf;
  }
}

__global__ void k_stats_fin(const double* __restrict__ s1, const double* __restrict__ s2,
                            const float* __restrict__ g, const float* __restrict__ bb,
                            int O, double M, double* __restrict__ scale, double* __restrict__ shift){
  int o = blockIdx.x*256 + threadIdx.x;
  if (o >= O) return;
  double mean = s1[o]/M;
  double var  = s2[o]/M - mean*mean;
  double sc = (double)g[o] / sqrt(var + EPSD);
  scale[o] = sc;
  shift[o] = (double)bb[o] - mean*sc;
}

// layer-5 1x1 conv, y5 layout (B,1024,N); f64 accumulate
__global__ __launch_bounds__(256) void k_conv5_v2(const float* __restrict__ xf_src,
                                                  const float* __restrict__ W5,
                                                  float* __restrict__ y5){
  int o = blockIdx.x, b = blockIdx.y;
  __shared__ float wsh[513];
  for (int t = threadIdx.x; t < 513; t += 256) wsh[t] = W5[(size_t)o*513 + t];
  __syncthreads();
  const float* xb = xf_src + (size_t)b*OCN;
  for (int n = threadIdx.x; n < NN; n += 256){
    double acc = 0.0;
    for (int c = 0; c < 513; c++) acc = fma((double)wsh[c], (double)xb[(size_t)c*NN + n], acc);
    y5[((size_t)b*1024 + o)*NN + n] = (float)acc;
  }
}

// per-channel BN stats over (B,N), atomic-free, fused finalize
__global__ __launch_bounds__(256) void k_stats5_v2(const float* __restrict__ y5,
                                                   const float* __restrict__ g,
                                                   const float* __restrict__ bb,
                                                   double* __restrict__ scale,
                                                   double* __restrict__ shift){
  int o = blockIdx.x;
  __shared__ double sh1[256], sh2[256];
  double a = 0.0, q = 0.0;
  for (int bn = threadIdx.x; bn < BB*NN; bn += 256){
    int b = bn >> 11, n = bn & 2047;
    double yv = (double)y5[((size_t)b*1024 + o)*NN + n];
    a += yv; q += yv*yv;
  }
  sh1[threadIdx.x] = a; sh2[threadIdx.x] = q;
  __syncthreads();
  for (int s = 128; s > 0; s >>= 1){
    if (threadIdx.x < s){ sh1[threadIdx.x] += sh1[threadIdx.x+s]; sh2[threadIdx.x] += sh2[threadIdx.x+s]; }
    __syncthreads();
  }
  if (threadIdx.x == 0){
    double M = (double)(BB*NN);
    double mean = sh1[0]/M;
    double var  = sh2[0]/M - mean*mean;
    double sc = (double)g[o]/sqrt(var + EPSD);
    scale[o] = sc;
    shift[o] = (double)bb[o] - mean*sc;
  }
}

// fused gmax/gavg + broadcast
__global__ __launch_bounds__(256) void k_final5_v2(const float* __restrict__ y5,
                                                   const double* __restrict__ scale,
                                                   const double* __restrict__ shift,
                                                   float* __restrict__ out){
  int o = blockIdx.x, b = blockIdx.y;
  __shared__ double smx[256], ssm[256];
  double sc = scale[o], sh = shift[o];
  double mx = -INFINITY, sm = 0.0;
  const float* yrow = y5 + ((size_t)b*1024 + o)*NN;
  for (int n = threadIdx.x; n < NN; n += 256){
    double z = sc*(double)yrow[n] + sh;
    z = z > 0.0 ? z : SLOPED*z;
    mx = fmax(mx, z); sm += z;
  }
  smx[threadIdx.x] = mx; ssm[threadIdx.x] = sm;
  __syncthreads();
  for (int s = 128; s > 0; s >>= 1){
    if (threadIdx.x < s){
      smx[threadIdx.x] = fmax(smx[threadIdx.x], smx[threadIdx.x+s]);
      ssm[threadIdx.x] += ssm[threadIdx.x+s];
    }
    __syncthreads();
  }
  float vg = (float)smx[0];
  float va = (float)(ssm[0]*(1.0/NN));
  float* ob = out + (size_t)b*OCN;
  for (int n = threadIdx.x; n < NN; n += 256){
    ob[(size_t)o*NN + n] = vg;
    ob[(size_t)(1024+o)*NN + n] = va;
  }
}

extern "C" void kernel_launch(void* const* d_in, const int* in_sizes, int n_in,
                              void* d_out, int out_size, void* d_ws, size_t ws_size,
                              hipStream_t stream){
  const float* xyz = (const float*)d_in[0];
  float* out = (float*)d_out;
  float* ws  = (float*)d_ws;

  const float* Wp[5] = {(const float*)d_in[1],(const float*)d_in[4],(const float*)d_in[7],(const float*)d_in[10],(const float*)d_in[13]};
  const float* Gp[5] = {(const float*)d_in[2],(const float*)d_in[5],(const float*)d_in[8],(const float*)d_in[11],(const float*)d_in[14]};
  const float* Bp[5] = {(const float*)d_in[3],(const float*)d_in[6],(const float*)d_in[9],(const float*)d_in[12],(const float*)d_in[15]};
  int Cin[4]  = {3, 64, 64, 128};
  int Oc[4]   = {64, 64, 128, 257};
  int xoutc[4]= {2051, 2115, 2179, 2307};

  float* pd   = ws + WS_PD;
  float* xA   = ws + WS_XA;
  float* xB   = ws + WS_XB;
  float* y5   = ws + WS_Y5;
  int*   idx  = (int*)(ws + WS_IDX);
  float* xx   = ws + WS_XX;
  double* s1d = (double*)(ws + WS_S1);
  double* s2d = (double*)(ws + WS_S2);
  double* scd = (double*)(ws + WS_SC);
  double* shd = (double*)(ws + WS_SH);

  k_prep_x0<<<cdiv(BB*NN,256), 256, 0, stream>>>(xyz, out, xA);

  for (int t = 0; t < 4; t++){
    int C = Cin[t], O = Oc[t];
    const float* xin = (t % 2 == 0) ? xA : xB;
    float* xnext = (t == 3) ? nullptr : ((t % 2 == 0) ? xB : xA);
    k_xx32<<<dim3(NN/256, BB), 256, 0, stream>>>(xin, C, xx);
    for (int b = 0; b < BB; b++){
      k_pd32<<<dim3(NN/TS, NN/TS), 256, 0, stream>>>(xin, C, b, xx, pd);
      k_topk_simple<<<NN/64, 64, 0, stream>>>(pd, b, idx);
    }
    hipMemsetAsync((void*)s1d, 0, 2048*sizeof(double), stream);
    int BS = (O <= 256) ? 256 : 320;
    size_t shmem = (size_t)(KK+1)*C*sizeof(float);
    k_edge<0><<<dim3(NN, BB), BS, shmem, stream>>>(xin, Wp[t], idx, C, O, s1d, s2d, nullptr, nullptr, nullptr, nullptr);
    k_stats_fin<<<cdiv(O,256), 256, 0, stream>>>(s1d, s2d, Gp[t], Bp[t], O, (double)((size_t)BB*NN*KK), scd, shd);
    k_edge<1><<<dim3(NN, BB), BS, shmem, stream>>>(xin, Wp[t], idx, C, O, nullptr, nullptr, scd, shd, out + (size_t)xoutc[t]*NN, xnext);
  }

  // ---- layer 5 (1x1 conv 513 -> 1024) + global pooling ----
  k_conv5_v2 <<<dim3(1024, BB), 256, 0, stream>>>(out + (size_t)2051*NN, Wp[4], y5);
  k_stats5_v2<<<1024, 256, 0, stream>>>(y5, Gp[4], Bp[4], scd, shd);
  k_final5_v2<<<dim3(1024, BB), 256, 0, stream>>>(y5, scd, shd, out);
}

// Round 10
// 9182.270 us; speedup vs baseline: 5.7106x; 5.7106x over previous
//
#include <hip/hip_runtime.h>
#include <math.h>

#define BB 8
#define NN 2048
#define KK 20
#define OCH 2564
#define OCN ((size_t)OCH*NN)
#define EPSD 1e-5
#define SLOPED 0.2
#define TS 64

// ---------------- ws layout (float offsets) — ALL DISJOINT while alive ----
// pd   [0          .. 4,194,304)
// ymx  [4,194,304  .. 8,404,992)   (B*N*257)
// ymn  [8,404,992  .. 12,615,680)
// xA   [12,615,680 .. 14,712,832)  (B*128*N)
// xB   [14,712,832 .. 16,809,984)
// u    [16,809,984 .. 17,336,320)  (N*257, one batch)
// v    [17,336,320 .. 17,862,656)
// idx  [17,862,656 .. 18,190,336)  (ints)
// xx   [18,190,336 .. 18,206,720)
// wtf  [18,206,720 .. 18,239,744)
// wtd  [18,239,744 .. 18,272,768)
// y5   [0 .. 16,777,216) overlay — pd/ymx/ymn/xA/xB all dead at layer 5
// s1/s2/sc/sh doubles beyond 18,272,768
#define WS_PD   ((size_t)0)
#define WS_YMX  ((size_t)4194304)
#define WS_YMN  ((size_t)8404992)
#define WS_XA   ((size_t)12615680)
#define WS_XB   ((size_t)14712832)
#define WS_U    ((size_t)16809984)
#define WS_V    ((size_t)17336320)
#define WS_IDX  ((size_t)17862656)
#define WS_XX   ((size_t)18190336)
#define WS_WTF  ((size_t)18206720)
#define WS_WTD  ((size_t)18239744)
#define WS_Y5   ((size_t)0)
#define WS_S1   ((size_t)18272768)
#define WS_S2   (WS_S1 + 2048)
#define WS_SC   (WS_S2 + 2048)
#define WS_SH   (WS_SC + 2048)

static inline int cdiv(int a, int b){ return (a+b-1)/b; }

// out[b, 2048+c, n] = xyz[b,n,c] ; xA[(b*3+c)*NN+n] = xyz
__global__ void k_prep_x0(const float* __restrict__ xyz, float* __restrict__ out,
                          float* __restrict__ xA){
  int id = blockIdx.x*256 + threadIdx.x;
  if (id >= BB*NN) return;
  int b = id / NN, n = id % NN;
  const float* p = xyz + ((size_t)b*NN + n)*3;
  float* o = out + (size_t)b*OCN + (size_t)2048*NN + n;
  o[0] = p[0]; o[(size_t)NN] = p[1]; o[2*(size_t)NN] = p[2];
  float* xa = xA + (size_t)b*3*NN + n;
  xa[0] = p[0]; xa[(size_t)NN] = p[1]; xa[2*(size_t)NN] = p[2];
}

// ---- KNN arithmetic: DO NOT TOUCH (validated canonical-f32, round 8) ----
__global__ void k_xx32(const float* __restrict__ x, int C, float* __restrict__ xx){
  int b = blockIdx.y;
  int n = blockIdx.x*256 + threadIdx.x;
  const float* p = x + (size_t)b*C*NN + n;
  float a;
  if (C <= 8){
    a = 0.f;
    for (int c = 0; c < C; c++){ float v = p[(size_t)c*NN]; float s = v*v; a = a + s; }
  } else {
    float r0,r1,r2,r3,r4,r5,r6,r7;
    { float v;
      v = p[0];            r0 = v*v;
      v = p[(size_t)1*NN]; r1 = v*v;
      v = p[(size_t)2*NN]; r2 = v*v;
      v = p[(size_t)3*NN]; r3 = v*v;
      v = p[(size_t)4*NN]; r4 = v*v;
      v = p[(size_t)5*NN]; r5 = v*v;
      v = p[(size_t)6*NN]; r6 = v*v;
      v = p[(size_t)7*NN]; r7 = v*v;
    }
    for (int i = 8; i < C; i += 8){
      float v;
      v = p[(size_t)(i+0)*NN]; r0 = r0 + v*v;
      v = p[(size_t)(i+1)*NN]; r1 = r1 + v*v;
      v = p[(size_t)(i+2)*NN]; r2 = r2 + v*v;
      v = p[(size_t)(i+3)*NN]; r3 = r3 + v*v;
      v = p[(size_t)(i+4)*NN]; r4 = r4 + v*v;
      v = p[(size_t)(i+5)*NN]; r5 = r5 + v*v;
      v = p[(size_t)(i+6)*NN]; r6 = r6 + v*v;
      v = p[(size_t)(i+7)*NN]; r7 = r7 + v*v;
    }
    a = ((r0+r1)+(r2+r3)) + ((r4+r5)+(r6+r7));
  }
  xx[b*NN + n] = a;
}

__global__ __launch_bounds__(256) void k_pd32(const float* __restrict__ x, int C, int b,
                     const float* __restrict__ xx, float* __restrict__ pd){
  __shared__ float As[8][TS];
  __shared__ float Bsh[8][TS];
  int n0 = blockIdx.y*TS, m0 = blockIdx.x*TS;
  int tid = threadIdx.x;
  int tx = tid % 16, ty = tid / 16;
  const float* xb = x + (size_t)b*C*NN;
  float acc[4][4] = {};
  for (int c0 = 0; c0 < C; c0 += 8){
    int r = tid / 64, col = tid % 64;
    #pragma unroll
    for (int rr = 0; rr < 2; rr++){
      int c = c0 + r + rr*4;
      float av = 0.f, bv = 0.f;
      if (c < C){ av = xb[(size_t)c*NN + n0 + col]; bv = xb[(size_t)c*NN + m0 + col]; }
      As[r+rr*4][col] = av; Bsh[r+rr*4][col] = bv;
    }
    __syncthreads();
    #pragma unroll
    for (int c = 0; c < 8; c++){
      float a[4], bbv[4];
      #pragma unroll
      for (int i=0;i<4;i++) a[i] = As[c][ty*4+i];
      #pragma unroll
      for (int j=0;j<4;j++) bbv[j] = Bsh[c][tx*4+j];
      #pragma unroll
      for (int i=0;i<4;i++)
        #pragma unroll
        for (int j=0;j<4;j++)
          acc[i][j] = fmaf(a[i], bbv[j], acc[i][j]);
    }
    __syncthreads();
  }
  const float* xxb = xx + b*NN;
  #pragma unroll
  for (int i=0;i<4;i++){
    int n = n0 + ty*4 + i;
    float xn = xxb[n];
    #pragma unroll
    for (int j=0;j<4;j++){
      int m = m0 + tx*4 + j;
      float t = 2.f*acc[i][j];
      pd[(size_t)n*NN + m] = (t - xn) - xxb[m];
    }
  }
}

// wave-ballot top-20; proven ≡ serial scan (r5->r6 bit-identical absmax)
__global__ __launch_bounds__(256) void k_topk(const float* __restrict__ pd, int b,
                                              int* __restrict__ idx){
  int lane = threadIdx.x & 63;
  int w = threadIdx.x >> 6;
  int n = blockIdx.x*4 + w;
  const float* row = pd + (size_t)n*NN;
  float vals[KK]; int inds[KK];
  #pragma unroll
  for (int i=0;i<KK;i++){ vals[i] = -INFINITY; inds[i] = 0; }
  for (int c = 0; c < NN/64; c++){
    float v = row[c*64 + lane];
    unsigned long long mask = __ballot(v > vals[KK-1]);
    while (mask){
      int l = __ffsll(mask) - 1;
      mask &= mask - 1ull;
      float bv = __shfl(v, l);
      if (!(bv > vals[KK-1])) continue;
      int bi = c*64 + l;
      #pragma unroll
      for (int i=KK-1;i>0;--i){
        if (vals[i-1] < bv){ vals[i]=vals[i-1]; inds[i]=inds[i-1]; }
      }
      bool done = false;
      #pragma unroll
      for (int i=0;i<KK;i++){
        bool pl = (!done) && (vals[i] < bv);
        if (pl){ vals[i]=bv; inds[i]=bi; done=true; }
      }
    }
  }
  if (lane == 0){
    int* op = idx + ((size_t)b*NN + n)*KK;
    #pragma unroll
    for (int i=0;i<KK;i++) op[i] = inds[i];
  }
}

// weight transpose: wtf[c][o]=W[o][c], wtd[c][o]=W[o][C+c]-W[o][c]
__global__ void k_wt(const float* __restrict__ W, float* __restrict__ wtf,
                     float* __restrict__ wtd, int Cin, int O){
  int id = blockIdx.x*256 + threadIdx.x;
  if (id >= Cin*O) return;
  int c = id / O, o = id % O;
  float wf = W[(size_t)o*(2*Cin) + c];
  float wc = W[(size_t)o*(2*Cin) + Cin + c];
  wtf[(size_t)c*O + o] = wf;
  wtd[(size_t)c*O + o] = wc - wf;
}

// u[n*O+o] = sum_c wtf[c][o]*x[b,c,n]; v with wtd  (one batch, f64 accumulate)
__global__ __launch_bounds__(256) void k_gemm_uv(
    const float* __restrict__ x, int C, int O, int b,
    const float* __restrict__ wtf, const float* __restrict__ wtd,
    float* __restrict__ u, float* __restrict__ v){
  __shared__ float Xs[8][TS];
  __shared__ float Wfs[8][TS];
  __shared__ float Wds[8][TS];
  int n0 = blockIdx.y*TS, o0 = blockIdx.x*TS;
  int tid = threadIdx.x, tx = tid%16, ty = tid/16;
  const float* xb = x + (size_t)b*C*NN;
  double au[4][4] = {};
  double av[4][4] = {};
  for (int c0 = 0; c0 < C; c0 += 8){
    int r = tid/64, col = tid%64;
    #pragma unroll
    for (int rr=0;rr<2;rr++){
      int c = c0 + r + rr*4;
      float xv=0.f, wfv=0.f, wdv=0.f;
      if (c < C){
        xv = xb[(size_t)c*NN + n0 + col];
        if (o0+col < O){
          wfv = wtf[(size_t)c*O + o0+col];
          wdv = wtd[(size_t)c*O + o0+col];
        }
      }
      Xs[r+rr*4][col]=xv; Wfs[r+rr*4][col]=wfv; Wds[r+rr*4][col]=wdv;
    }
    __syncthreads();
    #pragma unroll
    for (int c=0;c<8;c++){
      double a[4], f[4], d[4];
      #pragma unroll
      for (int i=0;i<4;i++) a[i] = (double)Xs[c][ty*4+i];
      #pragma unroll
      for (int j=0;j<4;j++) f[j] = (double)Wfs[c][tx*4+j];
      #pragma unroll
      for (int j=0;j<4;j++) d[j] = (double)Wds[c][tx*4+j];
      #pragma unroll
      for (int i=0;i<4;i++)
        #pragma unroll
        for (int j=0;j<4;j++){
          au[i][j] = fma(a[i], f[j], au[i][j]);
          av[i][j] = fma(a[i], d[j], av[i][j]);
        }
    }
    __syncthreads();
  }
  #pragma unroll
  for (int i=0;i<4;i++){
    int n = n0 + ty*4 + i;
    #pragma unroll
    for (int j=0;j<4;j++){
      int o = o0 + tx*4 + j;
      if (o < O){
        u[(size_t)n*O + o] = (float)au[i][j];
        v[(size_t)n*O + o] = (float)av[i][j];
      }
    }
  }
}

// gather: running max/min of y=u[idx]+v; f64 stats atomics (one batch)
#define NT 32
__global__ __launch_bounds__(256) void k_passB(
  const float* __restrict__ u, const float* __restrict__ v, const int* __restrict__ idx,
  int b, int O, int OT, float* __restrict__ ymax, float* __restrict__ ymin,
  double* __restrict__ s1, double* __restrict__ s2){
  __shared__ int ids[NT*KK];
  int n0 = blockIdx.x*NT;
  int tid = threadIdx.x;
  for (int t = tid; t < NT*KK; t += 256) ids[t] = idx[((size_t)b*NN + n0)*KK + t];
  __syncthreads();
  int nsplit = 256/OT;
  int ob = tid % OT, ns = tid / OT;
  int nper = NT / nsplit;
  for (int o = ob; o < O; o += 256){
    double s1p = 0.0, s2p = 0.0;
    for (int ni = ns*nper; ni < (ns+1)*nper; ni++){
      double su=0.0, sq=0.0;
      float mx=-INFINITY, mn=INFINITY;
      #pragma unroll
      for (int k=0;k<KK;k++){
        int j = ids[ni*KK + k];
        float uu = u[(size_t)j*O + o];
        double ud = (double)uu;
        su += ud; sq += ud*ud;
        mx = fmaxf(mx, uu); mn = fminf(mn, uu);
      }
      float vv = v[(size_t)(n0+ni)*O + o];
      double vd = (double)vv;
      s1p += su + (double)KK*vd;
      s2p += sq + 2.0*vd*su + (double)KK*vd*vd;
      size_t yo = ((size_t)b*NN + n0 + ni)*O + o;
      ymax[yo] = mx + vv; ymin[yo] = mn + vv;
    }
    atomicAdd(&s1[o], s1p);
    atomicAdd(&s2[o], s2p);
  }
}

__global__ void k_stats_fin(const double* __restrict__ s1, const double* __restrict__ s2,
                            const float* __restrict__ g, const float* __restrict__ bb,
                            int O, double M, double* __restrict__ scale, double* __restrict__ shift){
  int o = blockIdx.x*256 + threadIdx.x;
  if (o >= O) return;
  double mean = s1[o]/M;
  double var  = s2[o]/M - mean*mean;
  double sc = (double)g[o] / sqrt(var + EPSD);
  scale[o] = sc;
  shift[o] = (double)bb[o] - mean*sc;
}

// affine+lrelu (pick ymax/ymin by sign of scale), transpose -> (b,o,n)
__global__ __launch_bounds__(256) void k_passD(const float* __restrict__ ymax,
  const float* __restrict__ ymin, const double* __restrict__ scale,
  const double* __restrict__ shift, int O, float* __restrict__ xout,
  float* __restrict__ xnext){
  __shared__ float t[64][65];
  int b = blockIdx.z, n0 = blockIdx.y*64, o0 = blockIdx.x*64;
  int tid = threadIdx.x;
  int col = tid % 64, rr = tid / 64;
  int o = o0 + col;
  bool ov = (o < O);
  double sc = ov ? scale[o] : 0.0;
  double sh = ov ? shift[o] : 0.0;
  const float* src = (sc >= 0.0) ? ymax : ymin;
  for (int p = 0; p < 16; p++){
    int n = n0 + p*4 + rr;
    float y = ov ? src[((size_t)b*NN + n)*O + o] : 0.f;
    double z = sc*(double)y + sh;
    z = z > 0.0 ? z : SLOPED*z;
    t[p*4+rr][col] = (float)z;
  }
  __syncthreads();
  float* xb = xout + (size_t)b*OCN;
  for (int p = 0; p < 16; p++){
    int row = p*4 + rr;
    if (o0 + row < O){
      float val = t[col][row];
      xb[(size_t)(o0+row)*NN + n0 + col] = val;
      if (xnext) xnext[((size_t)b*O + o0+row)*NN + n0 + col] = val;
    }
  }
}

// layer-5 1x1 conv, y5 layout (B,1024,N); f64 accumulate
__global__ __launch_bounds__(256) void k_conv5_v2(const float* __restrict__ xf_src,
                                                  const float* __restrict__ W5,
                                                  float* __restrict__ y5){
  int o = blockIdx.x, b = blockIdx.y;
  __shared__ float wsh[513];
  for (int t = threadIdx.x; t < 513; t += 256) wsh[t] = W5[(size_t)o*513 + t];
  __syncthreads();
  const float* xb = xf_src + (size_t)b*OCN;
  for (int n = threadIdx.x; n < NN; n += 256){
    double acc = 0.0;
    for (int c = 0; c < 513; c++) acc = fma((double)wsh[c], (double)xb[(size_t)c*NN + n], acc);
    y5[((size_t)b*1024 + o)*NN + n] = (float)acc;
  }
}

__global__ __launch_bounds__(256) void k_stats5_v2(const float* __restrict__ y5,
                                                   const float* __restrict__ g,
                                                   const float* __restrict__ bb,
                                                   double* __restrict__ scale,
                                                   double* __restrict__ shift){
  int o = blockIdx.x;
  __shared__ double sh1[256], sh2[256];
  double a = 0.0, q = 0.0;
  for (int bn = threadIdx.x; bn < BB*NN; bn += 256){
    int b = bn >> 11, n = bn & 2047;
    double yv = (double)y5[((size_t)b*1024 + o)*NN + n];
    a += yv; q += yv*yv;
  }
  sh1[threadIdx.x] = a; sh2[threadIdx.x] = q;
  __syncthreads();
  for (int s = 128; s > 0; s >>= 1){
    if (threadIdx.x < s){ sh1[threadIdx.x] += sh1[threadIdx.x+s]; sh2[threadIdx.x] += sh2[threadIdx.x+s]; }
    __syncthreads();
  }
  if (threadIdx.x == 0){
    double M = (double)(BB*NN);
    double mean = sh1[0]/M;
    double var  = sh2[0]/M - mean*mean;
    double sc = (double)g[o]/sqrt(var + EPSD);
    scale[o] = sc;
    shift[o] = (double)bb[o] - mean*sc;
  }
}

__global__ __launch_bounds__(256) void k_final5_v2(const float* __restrict__ y5,
                                                   const double* __restrict__ scale,
                                                   const double* __restrict__ shift,
                                                   float* __restrict__ out){
  int o = blockIdx.x, b = blockIdx.y;
  __shared__ double smx[256], ssm[256];
  double sc = scale[o], sh = shift[o];
  double mx = -INFINITY, sm = 0.0;
  const float* yrow = y5 + ((size_t)b*1024 + o)*NN;
  for (int n = threadIdx.x; n < NN; n += 256){
    double z = sc*(double)yrow[n] + sh;
    z = z > 0.0 ? z : SLOPED*z;
    mx = fmax(mx, z); sm += z;
  }
  smx[threadIdx.x] = mx; ssm[threadIdx.x] = sm;
  __syncthreads();
  for (int s = 128; s > 0; s >>= 1){
    if (threadIdx.x < s){
      smx[threadIdx.x] = fmax(smx[threadIdx.x], smx[threadIdx.x+s]);
      ssm[threadIdx.x] += ssm[threadIdx.x+s];
    }
    __syncthreads();
  }
  float vg = (float)smx[0];
  float va = (float)(ssm[0]*(1.0/NN));
  float* ob = out + (size_t)b*OCN;
  for (int n = threadIdx.x; n < NN; n += 256){
    ob[(size_t)o*NN + n] = vg;
    ob[(size_t)(1024+o)*NN + n] = va;
  }
}

extern "C" void kernel_launch(void* const* d_in, const int* in_sizes, int n_in,
                              void* d_out, int out_size, void* d_ws, size_t ws_size,
                              hipStream_t stream){
  const float* xyz = (const float*)d_in[0];
  float* out = (float*)d_out;
  float* ws  = (float*)d_ws;

  const float* Wp[5] = {(const float*)d_in[1],(const float*)d_in[4],(const float*)d_in[7],(const float*)d_in[10],(const float*)d_in[13]};
  const float* Gp[5] = {(const float*)d_in[2],(const float*)d_in[5],(const float*)d_in[8],(const float*)d_in[11],(const float*)d_in[14]};
  const float* Bp[5] = {(const float*)d_in[3],(const float*)d_in[6],(const float*)d_in[9],(const float*)d_in[12],(const float*)d_in[15]};
  int Cin[4]  = {3, 64, 64, 128};
  int Oc[4]   = {64, 64, 128, 257};
  int xoutc[4]= {2051, 2115, 2179, 2307};

  float* pd   = ws + WS_PD;
  float* ymx  = ws + WS_YMX;
  float* ymn  = ws + WS_YMN;
  float* xA   = ws + WS_XA;
  float* xB   = ws + WS_XB;
  float* u    = ws + WS_U;
  float* v    = ws + WS_V;
  int*   idx  = (int*)(ws + WS_IDX);
  float* xx   = ws + WS_XX;
  float* wtf  = ws + WS_WTF;
  float* wtd  = ws + WS_WTD;
  float* y5   = ws + WS_Y5;
  double* s1d = (double*)(ws + WS_S1);
  double* s2d = (double*)(ws + WS_S2);
  double* scd = (double*)(ws + WS_SC);
  double* shd = (double*)(ws + WS_SH);

  k_prep_x0<<<cdiv(BB*NN,256), 256, 0, stream>>>(xyz, out, xA);

  for (int t = 0; t < 4; t++){
    int C = Cin[t], O = Oc[t];
    const float* xin = (t % 2 == 0) ? xA : xB;
    float* xnext = (t == 3) ? nullptr : ((t % 2 == 0) ? xB : xA);
    k_wt  <<<cdiv(C*O,256), 256, 0, stream>>>(Wp[t], wtf, wtd, C, O);
    k_xx32<<<dim3(NN/256, BB), 256, 0, stream>>>(xin, C, xx);
    hipMemsetAsync((void*)s1d, 0, 2048*sizeof(double), stream);
    int OT = (O <= 64) ? 64 : ((O <= 128) ? 128 : 256);
    for (int b = 0; b < BB; b++){
      k_pd32   <<<dim3(NN/TS, NN/TS), 256, 0, stream>>>(xin, C, b, xx, pd);
      k_topk   <<<NN/4, 256, 0, stream>>>(pd, b, idx);
      k_gemm_uv<<<dim3(cdiv(O,TS), NN/TS), 256, 0, stream>>>(xin, C, O, b, wtf, wtd, u, v);
      k_passB  <<<NN/NT, 256, 0, stream>>>(u, v, idx, b, O, OT, ymx, ymn, s1d, s2d);
    }
    k_stats_fin<<<cdiv(O,256), 256, 0, stream>>>(s1d, s2d, Gp[t], Bp[t], O, (double)((size_t)BB*NN*KK), scd, shd);
    k_passD<<<dim3(cdiv(O,TS), NN/TS, BB), 256, 0, stream>>>(ymx, ymn, scd, shd, O, out + (size_t)xoutc[t]*NN, xnext);
  }

  // ---- layer 5 (1x1 conv 513 -> 1024) + global pooling ----
  k_conv5_v2 <<<dim3(1024, BB), 256, 0, stream>>>(out + (size_t)2051*NN, Wp[4], y5);
  k_stats5_v2<<<1024, 256, 0, stream>>>(y5, Gp[4], Bp[4], scd, shd);
  k_final5_v2<<<dim3(1024, BB), 256, 0, stream>>>(y5, scd, shd, out);
}

// Round 11
// 5969.962 us; speedup vs baseline: 8.7834x; 1.5381x over previous
//
#include <hip/hip_runtime.h>
#include <math.h>

#define BB 8
#define NN 2048
#define KK 20
#define OCH 2564
#define OCN ((size_t)OCH*NN)
#define EPSD 1e-5
#define SLOPED 0.2
#define TS 64

// ---------------- ws layout (float offsets) — ALL DISJOINT while alive ----
// pd   [0          .. 4,194,304)
// ymx  [4,194,304  .. 8,404,992)   (B*N*257)
// ymn  [8,404,992  .. 12,615,680)
// xA   [12,615,680 .. 14,712,832)  (B*128*N)
// xB   [14,712,832 .. 16,809,984)
// u    [16,809,984 .. 21,020,672)  (B*N*257)
// v    [21,020,672 .. 25,231,360)
// idx  [25,231,360 .. 25,559,040)  (ints)
// xx   [25,559,040 .. 25,575,424)
// wtf  [25,575,424 .. 25,608,448)
// wtd  [25,608,448 .. 25,641,472)
// w5t  [25,641,472 .. 26,166,784)  (513*1024)
// y5   [0 .. 16,777,216) overlay — pd/ymx/ymn/xA/xB dead at layer 5
// s1/s2/sc/sh doubles beyond 26,166,784
#define WS_PD   ((size_t)0)
#define WS_YMX  ((size_t)4194304)
#define WS_YMN  ((size_t)8404992)
#define WS_XA   ((size_t)12615680)
#define WS_XB   ((size_t)14712832)
#define WS_U    ((size_t)16809984)
#define WS_V    ((size_t)21020672)
#define WS_IDX  ((size_t)25231360)
#define WS_XX   ((size_t)25559040)
#define WS_WTF  ((size_t)25575424)
#define WS_WTD  ((size_t)25608448)
#define WS_W5T  ((size_t)25641472)
#define WS_Y5   ((size_t)0)
#define WS_S1   ((size_t)26166784)
#define WS_S2   (WS_S1 + 2048)
#define WS_SC   (WS_S2 + 2048)
#define WS_SH   (WS_SC + 2048)

static inline int cdiv(int a, int b){ return (a+b-1)/b; }

// out[b, 2048+c, n] = xyz[b,n,c] ; xA[(b*3+c)*NN+n] = xyz
__global__ void k_prep_x0(const float* __restrict__ xyz, float* __restrict__ out,
                          float* __restrict__ xA){
  int id = blockIdx.x*256 + threadIdx.x;
  if (id >= BB*NN) return;
  int b = id / NN, n = id % NN;
  const float* p = xyz + ((size_t)b*NN + n)*3;
  float* o = out + (size_t)b*OCN + (size_t)2048*NN + n;
  o[0] = p[0]; o[(size_t)NN] = p[1]; o[2*(size_t)NN] = p[2];
  float* xa = xA + (size_t)b*3*NN + n;
  xa[0] = p[0]; xa[(size_t)NN] = p[1]; xa[2*(size_t)NN] = p[2];
}

// ---- KNN arithmetic: per-output chains validated round 8 (canonical f32) ----
__global__ void k_xx32(const float* __restrict__ x, int C, float* __restrict__ xx){
  int b = blockIdx.y;
  int n = blockIdx.x*256 + threadIdx.x;
  const float* p = x + (size_t)b*C*NN + n;
  float a;
  if (C <= 8){
    a = 0.f;
    for (int c = 0; c < C; c++){ float v = p[(size_t)c*NN]; float s = v*v; a = a + s; }
  } else {
    float r0,r1,r2,r3,r4,r5,r6,r7;
    { float v;
      v = p[0];            r0 = v*v;
      v = p[(size_t)1*NN]; r1 = v*v;
      v = p[(size_t)2*NN]; r2 = v*v;
      v = p[(size_t)3*NN]; r3 = v*v;
      v = p[(size_t)4*NN]; r4 = v*v;
      v = p[(size_t)5*NN]; r5 = v*v;
      v = p[(size_t)6*NN]; r6 = v*v;
      v = p[(size_t)7*NN]; r7 = v*v;
    }
    for (int i = 8; i < C; i += 8){
      float v;
      v = p[(size_t)(i+0)*NN]; r0 = r0 + v*v;
      v = p[(size_t)(i+1)*NN]; r1 = r1 + v*v;
      v = p[(size_t)(i+2)*NN]; r2 = r2 + v*v;
      v = p[(size_t)(i+3)*NN]; r3 = r3 + v*v;
      v = p[(size_t)(i+4)*NN]; r4 = r4 + v*v;
      v = p[(size_t)(i+5)*NN]; r5 = r5 + v*v;
      v = p[(size_t)(i+6)*NN]; r6 = r6 + v*v;
      v = p[(size_t)(i+7)*NN]; r7 = r7 + v*v;
    }
    a = ((r0+r1)+(r2+r3)) + ((r4+r5)+(r6+r7));
  }
  xx[b*NN + n] = a;
}

// 128x128 tile; per-output arithmetic identical to validated k_pd32:
// fmaf chain over c ascending (zero-padded chunk tails are exact no-ops),
// then (2*acc - xx[n]) - xx[m].
__global__ __launch_bounds__(256) void k_pd128(const float* __restrict__ x, int C, int b,
                     const float* __restrict__ xx, float* __restrict__ pd){
  __shared__ float As[8][128];
  __shared__ float Bs[8][128];
  int n0 = blockIdx.y*128, m0 = blockIdx.x*128;
  int tid = threadIdx.x;
  int ty = tid / 16, tx = tid % 16;
  const float* xb = x + (size_t)b*C*NN;
  float acc[8][8] = {};
  for (int c0 = 0; c0 < C; c0 += 8){
    #pragma unroll
    for (int rr = 0; rr < 4; rr++){
      int t2 = tid + rr*256;
      int c = t2 >> 7, col = t2 & 127;
      int cc = c0 + c;
      float av = 0.f, bv = 0.f;
      if (cc < C){ av = xb[(size_t)cc*NN + n0 + col]; bv = xb[(size_t)cc*NN + m0 + col]; }
      As[c][col] = av; Bs[c][col] = bv;
    }
    __syncthreads();
    #pragma unroll
    for (int c = 0; c < 8; c++){
      float a[8], bv[8];
      #pragma unroll
      for (int i=0;i<8;i++) a[i] = As[c][ty*8+i];
      #pragma unroll
      for (int j=0;j<8;j++) bv[j] = Bs[c][tx*8+j];
      #pragma unroll
      for (int i=0;i<8;i++)
        #pragma unroll
        for (int j=0;j<8;j++)
          acc[i][j] = fmaf(a[i], bv[j], acc[i][j]);
    }
    __syncthreads();
  }
  const float* xxb = xx + b*NN;
  #pragma unroll
  for (int i=0;i<8;i++){
    int n = n0 + ty*8 + i;
    float xn = xxb[n];
    #pragma unroll
    for (int j=0;j<8;j++){
      int m = m0 + tx*8 + j;
      float t = 2.f*acc[i][j];
      pd[(size_t)n*NN + m] = (t - xn) - xxb[m];
    }
  }
}

// wave-ballot top-20; proven ≡ serial scan (r5->r6 bit-identical absmax)
__global__ __launch_bounds__(256) void k_topk(const float* __restrict__ pd, int b,
                                              int* __restrict__ idx){
  int lane = threadIdx.x & 63;
  int w = threadIdx.x >> 6;
  int n = blockIdx.x*4 + w;
  const float* row = pd + (size_t)n*NN;
  float vals[KK]; int inds[KK];
  #pragma unroll
  for (int i=0;i<KK;i++){ vals[i] = -INFINITY; inds[i] = 0; }
  for (int c = 0; c < NN/64; c++){
    float v = row[c*64 + lane];
    unsigned long long mask = __ballot(v > vals[KK-1]);
    while (mask){
      int l = __ffsll(mask) - 1;
      mask &= mask - 1ull;
      float bv = __shfl(v, l);
      if (!(bv > vals[KK-1])) continue;
      int bi = c*64 + l;
      #pragma unroll
      for (int i=KK-1;i>0;--i){
        if (vals[i-1] < bv){ vals[i]=vals[i-1]; inds[i]=inds[i-1]; }
      }
      bool done = false;
      #pragma unroll
      for (int i=0;i<KK;i++){
        bool pl = (!done) && (vals[i] < bv);
        if (pl){ vals[i]=bv; inds[i]=bi; done=true; }
      }
    }
  }
  if (lane == 0){
    int* op = idx + ((size_t)b*NN + n)*KK;
    #pragma unroll
    for (int i=0;i<KK;i++) op[i] = inds[i];
  }
}

// weight transpose: wtf[c][o]=W[o][c], wtd[c][o]=W[o][C+c]-W[o][c]
__global__ void k_wt(const float* __restrict__ W, float* __restrict__ wtf,
                     float* __restrict__ wtd, int Cin, int O){
  int id = blockIdx.x*256 + threadIdx.x;
  if (id >= Cin*O) return;
  int c = id / O, o = id % O;
  float wf = W[(size_t)o*(2*Cin) + c];
  float wc = W[(size_t)o*(2*Cin) + Cin + c];
  wtf[(size_t)c*O + o] = wf;
  wtd[(size_t)c*O + o] = wc - wf;
}

// w5t[c*1024+o] = W5[o*513+c]
__global__ void k_wt5(const float* __restrict__ W5, float* __restrict__ w5t){
  int id = blockIdx.x*256 + threadIdx.x;
  if (id >= 513*1024) return;
  int c = id / 1024, o = id % 1024;
  w5t[(size_t)c*1024 + o] = W5[(size_t)o*513 + c];
}

// u[(b*N+n)*O+o] = sum_c wtf[c][o]*x; v with wtd  (all batches, f64 accumulate)
__global__ __launch_bounds__(256) void k_gemm_uv(
    const float* __restrict__ x, int C, int O,
    const float* __restrict__ wtf, const float* __restrict__ wtd,
    float* __restrict__ u, float* __restrict__ v){
  __shared__ float Xs[8][TS];
  __shared__ float Wfs[8][TS];
  __shared__ float Wds[8][TS];
  int b = blockIdx.z;
  int n0 = blockIdx.y*TS, o0 = blockIdx.x*TS;
  int tid = threadIdx.x, tx = tid%16, ty = tid/16;
  const float* xb = x + (size_t)b*C*NN;
  double au[4][4] = {};
  double av[4][4] = {};
  for (int c0 = 0; c0 < C; c0 += 8){
    int r = tid/64, col = tid%64;
    #pragma unroll
    for (int rr=0;rr<2;rr++){
      int c = c0 + r + rr*4;
      float xv=0.f, wfv=0.f, wdv=0.f;
      if (c < C){
        xv = xb[(size_t)c*NN + n0 + col];
        if (o0+col < O){
          wfv = wtf[(size_t)c*O + o0+col];
          wdv = wtd[(size_t)c*O + o0+col];
        }
      }
      Xs[r+rr*4][col]=xv; Wfs[r+rr*4][col]=wfv; Wds[r+rr*4][col]=wdv;
    }
    __syncthreads();
    #pragma unroll
    for (int c=0;c<8;c++){
      double a[4], f[4], d[4];
      #pragma unroll
      for (int i=0;i<4;i++) a[i] = (double)Xs[c][ty*4+i];
      #pragma unroll
      for (int j=0;j<4;j++) f[j] = (double)Wfs[c][tx*4+j];
      #pragma unroll
      for (int j=0;j<4;j++) d[j] = (double)Wds[c][tx*4+j];
      #pragma unroll
      for (int i=0;i<4;i++)
        #pragma unroll
        for (int j=0;j<4;j++){
          au[i][j] = fma(a[i], f[j], au[i][j]);
          av[i][j] = fma(a[i], d[j], av[i][j]);
        }
    }
    __syncthreads();
  }
  #pragma unroll
  for (int i=0;i<4;i++){
    int n = n0 + ty*4 + i;
    #pragma unroll
    for (int j=0;j<4;j++){
      int o = o0 + tx*4 + j;
      if (o < O){
        u[((size_t)b*NN + n)*O + o] = (float)au[i][j];
        v[((size_t)b*NN + n)*O + o] = (float)av[i][j];
      }
    }
  }
}

// gather: running max/min of y=u[idx]+v; f64 stats atomics (all batches)
#define NT 32
__global__ __launch_bounds__(256) void k_passB(
  const float* __restrict__ u, const float* __restrict__ v, const int* __restrict__ idx,
  int O, int OT, float* __restrict__ ymax, float* __restrict__ ymin,
  double* __restrict__ s1, double* __restrict__ s2){
  __shared__ int ids[NT*KK];
  int b = blockIdx.y, n0 = blockIdx.x*NT;
  int tid = threadIdx.x;
  for (int t = tid; t < NT*KK; t += 256) ids[t] = idx[((size_t)b*NN + n0)*KK + t];
  __syncthreads();
  int nsplit = 256/OT;
  int ob = tid % OT, ns = tid / OT;
  int nper = NT / nsplit;
  const float* ub = u + (size_t)b*NN*O;
  const float* vb = v + (size_t)b*NN*O;
  for (int o = ob; o < O; o += 256){
    double s1p = 0.0, s2p = 0.0;
    for (int ni = ns*nper; ni < (ns+1)*nper; ni++){
      double su=0.0, sq=0.0;
      float mx=-INFINITY, mn=INFINITY;
      #pragma unroll
      for (int k=0;k<KK;k++){
        int j = ids[ni*KK + k];
        float uu = ub[(size_t)j*O + o];
        double ud = (double)uu;
        su += ud; sq += ud*ud;
        mx = fmaxf(mx, uu); mn = fminf(mn, uu);
      }
      float vv = vb[(size_t)(n0+ni)*O + o];
      double vd = (double)vv;
      s1p += su + (double)KK*vd;
      s2p += sq + 2.0*vd*su + (double)KK*vd*vd;
      size_t yo = ((size_t)b*NN + n0 + ni)*O + o;
      ymax[yo] = mx + vv; ymin[yo] = mn + vv;
    }
    atomicAdd(&s1[o], s1p);
    atomicAdd(&s2[o], s2p);
  }
}

__global__ void k_stats_fin(const double* __restrict__ s1, const double* __restrict__ s2,
                            const float* __restrict__ g, const float* __restrict__ bb,
                            int O, double M, double* __restrict__ scale, double* __restrict__ shift){
  int o = blockIdx.x*256 + threadIdx.x;
  if (o >= O) return;
  double mean = s1[o]/M;
  double var  = s2[o]/M - mean*mean;
  double sc = (double)g[o] / sqrt(var + EPSD);
  scale[o] = sc;
  shift[o] = (double)bb[o] - mean*sc;
}

// affine+lrelu (pick ymax/ymin by sign of scale), transpose -> (b,o,n)
__global__ __launch_bounds__(256) void k_passD(const float* __restrict__ ymax,
  const float* __restrict__ ymin, const double* __restrict__ scale,
  const double* __restrict__ shift, int O, float* __restrict__ xout,
  float* __restrict__ xnext){
  __shared__ float t[64][65];
  int b = blockIdx.z, n0 = blockIdx.y*64, o0 = blockIdx.x*64;
  int tid = threadIdx.x;
  int col = tid % 64, rr = tid / 64;
  int o = o0 + col;
  bool ov = (o < O);
  double sc = ov ? scale[o] : 0.0;
  double sh = ov ? shift[o] : 0.0;
  const float* src = (sc >= 0.0) ? ymax : ymin;
  for (int p = 0; p < 16; p++){
    int n = n0 + p*4 + rr;
    float y = ov ? src[((size_t)b*NN + n)*O + o] : 0.f;
    double z = sc*(double)y + sh;
    z = z > 0.0 ? z : SLOPED*z;
    t[p*4+rr][col] = (float)z;
  }
  __syncthreads();
  float* xb = xout + (size_t)b*OCN;
  for (int p = 0; p < 16; p++){
    int row = p*4 + rr;
    if (o0 + row < O){
      float val = t[col][row];
      xb[(size_t)(o0+row)*NN + n0 + col] = val;
      if (xnext) xnext[((size_t)b*O + o0+row)*NN + n0 + col] = val;
    }
  }
}

// layer-5 conv as tiled f32 GEMM: y5[(b*1024+o)*NN+n] = sum_c w5t[c][o]*xf[b,c,n]
__global__ __launch_bounds__(256) void k_conv5g(const float* __restrict__ xf,
                                                const float* __restrict__ w5t,
                                                float* __restrict__ y5){
  __shared__ float Wsh[8][128];
  __shared__ float Xs[8][128];
  int o0 = blockIdx.x*128, n0 = blockIdx.y*128, b = blockIdx.z;
  int tid = threadIdx.x;
  int ty = tid / 16, tx = tid % 16;
  const float* xb = xf + (size_t)b*OCN;
  float acc[8][8] = {};
  for (int c0 = 0; c0 < 513; c0 += 8){
    #pragma unroll
    for (int rr = 0; rr < 4; rr++){
      int t2 = tid + rr*256;
      int c = t2 >> 7, col = t2 & 127;
      int cc = c0 + c;
      float wv = 0.f, xv = 0.f;
      if (cc < 513){
        wv = w5t[(size_t)cc*1024 + o0 + col];
        xv = xb[(size_t)cc*NN + n0 + col];
      }
      Wsh[c][col] = wv; Xs[c][col] = xv;
    }
    __syncthreads();
    #pragma unroll
    for (int c = 0; c < 8; c++){
      float wr[8], xr[8];
      #pragma unroll
      for (int i=0;i<8;i++) wr[i] = Wsh[c][ty*8+i];
      #pragma unroll
      for (int j=0;j<8;j++) xr[j] = Xs[c][tx*8+j];
      #pragma unroll
      for (int i=0;i<8;i++)
        #pragma unroll
        for (int j=0;j<8;j++)
          acc[i][j] = fmaf(wr[i], xr[j], acc[i][j]);
    }
    __syncthreads();
  }
  #pragma unroll
  for (int i=0;i<8;i++){
    int o = o0 + ty*8 + i;
    #pragma unroll
    for (int j=0;j<8;j++){
      int n = n0 + tx*8 + j;
      y5[((size_t)b*1024 + o)*NN + n] = acc[i][j];
    }
  }
}

__global__ __launch_bounds__(256) void k_stats5_v2(const float* __restrict__ y5,
                                                   const float* __restrict__ g,
                                                   const float* __restrict__ bb,
                                                   double* __restrict__ scale,
                                                   double* __restrict__ shift){
  int o = blockIdx.x;
  __shared__ double sh1[256], sh2[256];
  double a = 0.0, q = 0.0;
  for (int bn = threadIdx.x; bn < BB*NN; bn += 256){
    int b = bn >> 11, n = bn & 2047;
    double yv = (double)y5[((size_t)b*1024 + o)*NN + n];
    a += yv; q += yv*yv;
  }
  sh1[threadIdx.x] = a; sh2[threadIdx.x] = q;
  __syncthreads();
  for (int s = 128; s > 0; s >>= 1){
    if (threadIdx.x < s){ sh1[threadIdx.x] += sh1[threadIdx.x+s]; sh2[threadIdx.x] += sh2[threadIdx.x+s]; }
    __syncthreads();
  }
  if (threadIdx.x == 0){
    double M = (double)(BB*NN);
    double mean = sh1[0]/M;
    double var  = sh2[0]/M - mean*mean;
    double sc = (double)g[o]/sqrt(var + EPSD);
    scale[o] = sc;
    shift[o] = (double)bb[o] - mean*sc;
  }
}

__global__ __launch_bounds__(256) void k_final5_v2(const float* __restrict__ y5,
                                                   const double* __restrict__ scale,
                                                   const double* __restrict__ shift,
                                                   float* __restrict__ out){
  int o = blockIdx.x, b = blockIdx.y;
  __shared__ double smx[256], ssm[256];
  double sc = scale[o], sh = shift[o];
  double mx = -INFINITY, sm = 0.0;
  const float* yrow = y5 + ((size_t)b*1024 + o)*NN;
  for (int n = threadIdx.x; n < NN; n += 256){
    double z = sc*(double)yrow[n] + sh;
    z = z > 0.0 ? z : SLOPED*z;
    mx = fmax(mx, z); sm += z;
  }
  smx[threadIdx.x] = mx; ssm[threadIdx.x] = sm;
  __syncthreads();
  for (int s = 128; s > 0; s >>= 1){
    if (threadIdx.x < s){
      smx[threadIdx.x] = fmax(smx[threadIdx.x], smx[threadIdx.x+s]);
      ssm[threadIdx.x] += ssm[threadIdx.x+s];
    }
    __syncthreads();
  }
  float vg = (float)smx[0];
  float va = (float)(ssm[0]*(1.0/NN));
  float* ob = out + (size_t)b*OCN;
  for (int n = threadIdx.x; n < NN; n += 256){
    ob[(size_t)o*NN + n] = vg;
    ob[(size_t)(1024+o)*NN + n] = va;
  }
}

extern "C" void kernel_launch(void* const* d_in, const int* in_sizes, int n_in,
                              void* d_out, int out_size, void* d_ws, size_t ws_size,
                              hipStream_t stream){
  const float* xyz = (const float*)d_in[0];
  float* out = (float*)d_out;
  float* ws  = (float*)d_ws;

  const float* Wp[5] = {(const float*)d_in[1],(const float*)d_in[4],(const float*)d_in[7],(const float*)d_in[10],(const float*)d_in[13]};
  const float* Gp[5] = {(const float*)d_in[2],(const float*)d_in[5],(const float*)d_in[8],(const float*)d_in[11],(const float*)d_in[14]};
  const float* Bp[5] = {(const float*)d_in[3],(const float*)d_in[6],(const float*)d_in[9],(const float*)d_in[12],(const float*)d_in[15]};
  int Cin[4]  = {3, 64, 64, 128};
  int Oc[4]   = {64, 64, 128, 257};
  int xoutc[4]= {2051, 2115, 2179, 2307};

  float* pd   = ws + WS_PD;
  float* ymx  = ws + WS_YMX;
  float* ymn  = ws + WS_YMN;
  float* xA   = ws + WS_XA;
  float* xB   = ws + WS_XB;
  float* u    = ws + WS_U;
  float* v    = ws + WS_V;
  int*   idx  = (int*)(ws + WS_IDX);
  float* xx   = ws + WS_XX;
  float* wtf  = ws + WS_WTF;
  float* wtd  = ws + WS_WTD;
  float* w5t  = ws + WS_W5T;
  float* y5   = ws + WS_Y5;
  double* s1d = (double*)(ws + WS_S1);
  double* s2d = (double*)(ws + WS_S2);
  double* scd = (double*)(ws + WS_SC);
  double* shd = (double*)(ws + WS_SH);

  k_prep_x0<<<cdiv(BB*NN,256), 256, 0, stream>>>(xyz, out, xA);

  for (int t = 0; t < 4; t++){
    int C = Cin[t], O = Oc[t];
    const float* xin = (t % 2 == 0) ? xA : xB;
    float* xnext = (t == 3) ? nullptr : ((t % 2 == 0) ? xB : xA);
    k_wt  <<<cdiv(C*O,256), 256, 0, stream>>>(Wp[t], wtf, wtd, C, O);
    k_xx32<<<dim3(NN/256, BB), 256, 0, stream>>>(xin, C, xx);
    hipMemsetAsync((void*)s1d, 0, 2048*sizeof(double), stream);
    int OT = (O <= 64) ? 64 : ((O <= 128) ? 128 : 256);
    for (int b = 0; b < BB; b++){
      k_pd128<<<dim3(NN/128, NN/128), 256, 0, stream>>>(xin, C, b, xx, pd);
      k_topk <<<NN/4, 256, 0, stream>>>(pd, b, idx);
    }
    k_gemm_uv<<<dim3(cdiv(O,TS), NN/TS, BB), 256, 0, stream>>>(xin, C, O, wtf, wtd, u, v);
    k_passB  <<<dim3(NN/NT, BB), 256, 0, stream>>>(u, v, idx, O, OT, ymx, ymn, s1d, s2d);
    k_stats_fin<<<cdiv(O,256), 256, 0, stream>>>(s1d, s2d, Gp[t], Bp[t], O, (double)((size_t)BB*NN*KK), scd, shd);
    k_passD<<<dim3(cdiv(O,TS), NN/TS, BB), 256, 0, stream>>>(ymx, ymn, scd, shd, O, out + (size_t)xoutc[t]*NN, xnext);
  }

  // ---- layer 5 (1x1 conv 513 -> 1024) + global pooling ----
  k_wt5   <<<cdiv(513*1024,256), 256, 0, stream>>>(Wp[4], w5t);
  k_conv5g<<<dim3(1024/128, NN/128, BB), 256, 0, stream>>>(out + (size_t)2051*NN, w5t, y5);
  k_stats5_v2<<<1024, 256, 0, stream>>>(y5, Gp[4], Bp[4], scd, shd);
  k_final5_v2<<<dim3(1024, BB), 256, 0, stream>>>(y5, scd, shd, out);
}

// Round 12
// 3778.427 us; speedup vs baseline: 13.8779x; 1.5800x over previous
//
#include <hip/hip_runtime.h>
#include <math.h>

#define BB 8
#define NN 2048
#define KK 20
#define OCH 2564
#define OCN ((size_t)OCH*NN)
#define EPSD 1e-5
#define SLOPED 0.2
#define TS 64

// ---------------- ws layout (float offsets) — ALL DISJOINT while alive ----
#define WS_PD   ((size_t)0)
#define WS_YMX  ((size_t)4194304)
#define WS_YMN  ((size_t)8404992)
#define WS_XA   ((size_t)12615680)
#define WS_XB   ((size_t)14712832)
#define WS_U    ((size_t)16809984)
#define WS_V    ((size_t)21020672)
#define WS_IDX  ((size_t)25231360)
#define WS_XX   ((size_t)25559040)
#define WS_WTF  ((size_t)25575424)
#define WS_WTD  ((size_t)25608448)
#define WS_W5T  ((size_t)25641472)
#define WS_Y5   ((size_t)0)
#define WS_S1   ((size_t)26166784)
#define WS_S2   (WS_S1 + 2048)
#define WS_SC   (WS_S2 + 2048)
#define WS_SH   (WS_SC + 2048)

static inline int cdiv(int a, int b){ return (a+b-1)/b; }

// out[b, 2048+c, n] = xyz[b,n,c] ; xA[(b*3+c)*NN+n] = xyz
__global__ void k_prep_x0(const float* __restrict__ xyz, float* __restrict__ out,
                          float* __restrict__ xA){
  int id = blockIdx.x*256 + threadIdx.x;
  if (id >= BB*NN) return;
  int b = id / NN, n = id % NN;
  const float* p = xyz + ((size_t)b*NN + n)*3;
  float* o = out + (size_t)b*OCN + (size_t)2048*NN + n;
  o[0] = p[0]; o[(size_t)NN] = p[1]; o[2*(size_t)NN] = p[2];
  float* xa = xA + (size_t)b*3*NN + n;
  xa[0] = p[0]; xa[(size_t)NN] = p[1]; xa[2*(size_t)NN] = p[2];
}

// ---- KNN arithmetic: per-output chains validated round 8 (canonical f32) ----
__global__ void k_xx32(const float* __restrict__ x, int C, float* __restrict__ xx){
  int b = blockIdx.y;
  int n = blockIdx.x*256 + threadIdx.x;
  const float* p = x + (size_t)b*C*NN + n;
  float a;
  if (C <= 8){
    a = 0.f;
    for (int c = 0; c < C; c++){ float v = p[(size_t)c*NN]; float s = v*v; a = a + s; }
  } else {
    float r0,r1,r2,r3,r4,r5,r6,r7;
    { float v;
      v = p[0];            r0 = v*v;
      v = p[(size_t)1*NN]; r1 = v*v;
      v = p[(size_t)2*NN]; r2 = v*v;
      v = p[(size_t)3*NN]; r3 = v*v;
      v = p[(size_t)4*NN]; r4 = v*v;
      v = p[(size_t)5*NN]; r5 = v*v;
      v = p[(size_t)6*NN]; r6 = v*v;
      v = p[(size_t)7*NN]; r7 = v*v;
    }
    for (int i = 8; i < C; i += 8){
      float v;
      v = p[(size_t)(i+0)*NN]; r0 = r0 + v*v;
      v = p[(size_t)(i+1)*NN]; r1 = r1 + v*v;
      v = p[(size_t)(i+2)*NN]; r2 = r2 + v*v;
      v = p[(size_t)(i+3)*NN]; r3 = r3 + v*v;
      v = p[(size_t)(i+4)*NN]; r4 = r4 + v*v;
      v = p[(size_t)(i+5)*NN]; r5 = r5 + v*v;
      v = p[(size_t)(i+6)*NN]; r6 = r6 + v*v;
      v = p[(size_t)(i+7)*NN]; r7 = r7 + v*v;
    }
    a = ((r0+r1)+(r2+r3)) + ((r4+r5)+(r6+r7));
  }
  xx[b*NN + n] = a;
}

// 128x128 tile; per-output fmaf chain identical to validated version;
// bank-conflict-free operand reads (Bs read has 16 consecutive addrs per j).
__global__ __launch_bounds__(256) void k_pd128(const float* __restrict__ x, int C, int b,
                     const float* __restrict__ xx, float* __restrict__ pd){
  __shared__ float As[8][128];
  __shared__ float Bs[8][128];
  int n0 = blockIdx.y*128, m0 = blockIdx.x*128;
  int tid = threadIdx.x;
  int ty = tid / 16, tx = tid % 16;
  const float* xb = x + (size_t)b*C*NN;
  float acc[8][8] = {};
  for (int c0 = 0; c0 < C; c0 += 8){
    #pragma unroll
    for (int rr = 0; rr < 4; rr++){
      int t2 = tid + rr*256;
      int c = t2 >> 7, col = t2 & 127;
      int cc = c0 + c;
      float av = 0.f, bv = 0.f;
      if (cc < C){ av = xb[(size_t)cc*NN + n0 + col]; bv = xb[(size_t)cc*NN + m0 + col]; }
      As[c][col] = av; Bs[c][col] = bv;
    }
    __syncthreads();
    #pragma unroll
    for (int c = 0; c < 8; c++){
      float a[8], bv[8];
      #pragma unroll
      for (int i=0;i<8;i++) a[i] = As[c][ty*8+i];
      #pragma unroll
      for (int j=0;j<8;j++) bv[j] = Bs[c][j*16+tx];
      #pragma unroll
      for (int i=0;i<8;i++)
        #pragma unroll
        for (int j=0;j<8;j++)
          acc[i][j] = fmaf(a[i], bv[j], acc[i][j]);
    }
    __syncthreads();
  }
  const float* xxb = xx + b*NN;
  #pragma unroll
  for (int i=0;i<8;i++){
    int n = n0 + ty*8 + i;
    float xn = xxb[n];
    #pragma unroll
    for (int j=0;j<8;j++){
      int m = m0 + j*16 + tx;
      float t = 2.f*acc[i][j];
      pd[(size_t)n*NN + m] = (t - xn) - xxb[m];
    }
  }
}

// deterministic top-20: per-lane top-20 over its 32 strided elements
// (ascending-m strict-compare insertion), then 20 rounds of wave argmax
// (value desc, index asc) with winner-lane head pop.
// Selected SET identical to validated serial/ballot scans.
__global__ __launch_bounds__(256) void k_topk(const float* __restrict__ pd, int b,
                                              int* __restrict__ idx){
  int lane = threadIdx.x & 63;
  int w = threadIdx.x >> 6;
  int n = blockIdx.x*4 + w;
  const float* row = pd + (size_t)n*NN;
  float vals[KK]; int inds[KK];
  #pragma unroll
  for (int i=0;i<KK;i++){ vals[i] = -INFINITY; inds[i] = NN; }
  for (int c = 0; c < NN/64; c++){
    int m = c*64 + lane;
    float v = row[m];
    if (v > vals[KK-1]){
      #pragma unroll
      for (int i=KK-1;i>0;--i){
        if (vals[i-1] < v){ vals[i]=vals[i-1]; inds[i]=inds[i-1]; }
      }
      bool done = false;
      #pragma unroll
      for (int i=0;i<KK;i++){
        bool pl = (!done) && (vals[i] < v);
        if (pl){ vals[i]=v; inds[i]=m; done=true; }
      }
    }
  }
  int* op = idx + ((size_t)b*NN + n)*KK;
  #pragma unroll 1
  for (int r = 0; r < KK; r++){
    float bv = vals[0]; int bi = inds[0];
    #pragma unroll
    for (int s = 1; s < 64; s <<= 1){
      float ov = __shfl_xor(bv, s);
      int   oi = __shfl_xor(bi, s);
      if (ov > bv || (ov == bv && oi < bi)){ bv = ov; bi = oi; }
    }
    if (inds[0] == bi){   // exactly one lane owns index bi
      #pragma unroll
      for (int i=0;i<KK-1;i++){ vals[i]=vals[i+1]; inds[i]=inds[i+1]; }
      vals[KK-1] = -INFINITY; inds[KK-1] = NN;
    }
    if (lane == 0) op[r] = bi;
  }
}

// weight transpose: wtf[c][o]=W[o][c], wtd[c][o]=W[o][C+c]-W[o][c]
__global__ void k_wt(const float* __restrict__ W, float* __restrict__ wtf,
                     float* __restrict__ wtd, int Cin, int O){
  int id = blockIdx.x*256 + threadIdx.x;
  if (id >= Cin*O) return;
  int c = id / O, o = id % O;
  float wf = W[(size_t)o*(2*Cin) + c];
  float wc = W[(size_t)o*(2*Cin) + Cin + c];
  wtf[(size_t)c*O + o] = wf;
  wtd[(size_t)c*O + o] = wc - wf;
}

// w5t[c*1024+o] = W5[o*513+c]
__global__ void k_wt5(const float* __restrict__ W5, float* __restrict__ w5t){
  int id = blockIdx.x*256 + threadIdx.x;
  if (id >= 513*1024) return;
  int c = id / 1024, o = id % 1024;
  w5t[(size_t)c*1024 + o] = W5[(size_t)o*513 + c];
}

// u[(b*N+n)*O+o] = sum_c wtf[c][o]*x; v with wtd  (all batches, f64 accumulate)
__global__ __launch_bounds__(256) void k_gemm_uv(
    const float* __restrict__ x, int C, int O,
    const float* __restrict__ wtf, const float* __restrict__ wtd,
    float* __restrict__ u, float* __restrict__ v){
  __shared__ float Xs[8][TS];
  __shared__ float Wfs[8][TS];
  __shared__ float Wds[8][TS];
  int b = blockIdx.z;
  int n0 = blockIdx.y*TS, o0 = blockIdx.x*TS;
  int tid = threadIdx.x, tx = tid%16, ty = tid/16;
  const float* xb = x + (size_t)b*C*NN;
  double au[4][4] = {};
  double av[4][4] = {};
  for (int c0 = 0; c0 < C; c0 += 8){
    int r = tid/64, col = tid%64;
    #pragma unroll
    for (int rr=0;rr<2;rr++){
      int c = c0 + r + rr*4;
      float xv=0.f, wfv=0.f, wdv=0.f;
      if (c < C){
        xv = xb[(size_t)c*NN + n0 + col];
        if (o0+col < O){
          wfv = wtf[(size_t)c*O + o0+col];
          wdv = wtd[(size_t)c*O + o0+col];
        }
      }
      Xs[r+rr*4][col]=xv; Wfs[r+rr*4][col]=wfv; Wds[r+rr*4][col]=wdv;
    }
    __syncthreads();
    #pragma unroll
    for (int c=0;c<8;c++){
      double a[4], f[4], d[4];
      #pragma unroll
      for (int i=0;i<4;i++) a[i] = (double)Xs[c][ty*4+i];
      #pragma unroll
      for (int j=0;j<4;j++) f[j] = (double)Wfs[c][tx*4+j];
      #pragma unroll
      for (int j=0;j<4;j++) d[j] = (double)Wds[c][tx*4+j];
      #pragma unroll
      for (int i=0;i<4;i++)
        #pragma unroll
        for (int j=0;j<4;j++){
          au[i][j] = fma(a[i], f[j], au[i][j]);
          av[i][j] = fma(a[i], d[j], av[i][j]);
        }
    }
    __syncthreads();
  }
  #pragma unroll
  for (int i=0;i<4;i++){
    int n = n0 + ty*4 + i;
    #pragma unroll
    for (int j=0;j<4;j++){
      int o = o0 + tx*4 + j;
      if (o < O){
        u[((size_t)b*NN + n)*O + o] = (float)au[i][j];
        v[((size_t)b*NN + n)*O + o] = (float)av[i][j];
      }
    }
  }
}

// gather: running max/min of y=u[idx]+v; f64 stats atomics (all batches)
#define NT 32
__global__ __launch_bounds__(256) void k_passB(
  const float* __restrict__ u, const float* __restrict__ v, const int* __restrict__ idx,
  int O, int OT, float* __restrict__ ymax, float* __restrict__ ymin,
  double* __restrict__ s1, double* __restrict__ s2){
  __shared__ int ids[NT*KK];
  int b = blockIdx.y, n0 = blockIdx.x*NT;
  int tid = threadIdx.x;
  for (int t = tid; t < NT*KK; t += 256) ids[t] = idx[((size_t)b*NN + n0)*KK + t];
  __syncthreads();
  int nsplit = 256/OT;
  int ob = tid % OT, ns = tid / OT;
  int nper = NT / nsplit;
  const float* ub = u + (size_t)b*NN*O;
  const float* vb = v + (size_t)b*NN*O;
  for (int o = ob; o < O; o += 256){
    double s1p = 0.0, s2p = 0.0;
    for (int ni = ns*nper; ni < (ns+1)*nper; ni++){
      double su=0.0, sq=0.0;
      float mx=-INFINITY, mn=INFINITY;
      #pragma unroll
      for (int k=0;k<KK;k++){
        int j = ids[ni*KK + k];
        float uu = ub[(size_t)j*O + o];
        double ud = (double)uu;
        su += ud; sq += ud*ud;
        mx = fmaxf(mx, uu); mn = fminf(mn, uu);
      }
      float vv = vb[(size_t)(n0+ni)*O + o];
      double vd = (double)vv;
      s1p += su + (double)KK*vd;
      s2p += sq + 2.0*vd*su + (double)KK*vd*vd;
      size_t yo = ((size_t)b*NN + n0 + ni)*O + o;
      ymax[yo] = mx + vv; ymin[yo] = mn + vv;
    }
    atomicAdd(&s1[o], s1p);
    atomicAdd(&s2[o], s2p);
  }
}

__global__ void k_stats_fin(const double* __restrict__ s1, const double* __restrict__ s2,
                            const float* __restrict__ g, const float* __restrict__ bb,
                            int O, double M, double* __restrict__ scale, double* __restrict__ shift){
  int o = blockIdx.x*256 + threadIdx.x;
  if (o >= O) return;
  double mean = s1[o]/M;
  double var  = s2[o]/M - mean*mean;
  double sc = (double)g[o] / sqrt(var + EPSD);
  scale[o] = sc;
  shift[o] = (double)bb[o] - mean*sc;
}

// affine+lrelu (pick ymax/ymin by sign of scale), transpose -> (b,o,n)
__global__ __launch_bounds__(256) void k_passD(const float* __restrict__ ymax,
  const float* __restrict__ ymin, const double* __restrict__ scale,
  const double* __restrict__ shift, int O, float* __restrict__ xout,
  float* __restrict__ xnext){
  __shared__ float t[64][65];
  int b = blockIdx.z, n0 = blockIdx.y*64, o0 = blockIdx.x*64;
  int tid = threadIdx.x;
  int col = tid % 64, rr = tid / 64;
  int o = o0 + col;
  bool ov = (o < O);
  double sc = ov ? scale[o] : 0.0;
  double sh = ov ? shift[o] : 0.0;
  const float* src = (sc >= 0.0) ? ymax : ymin;
  for (int p = 0; p < 16; p++){
    int n = n0 + p*4 + rr;
    float y = ov ? src[((size_t)b*NN + n)*O + o] : 0.f;
    double z = sc*(double)y + sh;
    z = z > 0.0 ? z : SLOPED*z;
    t[p*4+rr][col] = (float)z;
  }
  __syncthreads();
  float* xb = xout + (size_t)b*OCN;
  for (int p = 0; p < 16; p++){
    int row = p*4 + rr;
    if (o0 + row < O){
      float val = t[col][row];
      xb[(size_t)(o0+row)*NN + n0 + col] = val;
      if (xnext) xnext[((size_t)b*O + o0+row)*NN + n0 + col] = val;
    }
  }
}

// layer-5 conv as tiled f32 GEMM; bank-conflict-free reads like k_pd128
__global__ __launch_bounds__(256) void k_conv5g(const float* __restrict__ xf,
                                                const float* __restrict__ w5t,
                                                float* __restrict__ y5){
  __shared__ float Wsh[8][128];
  __shared__ float Xs[8][128];
  int o0 = blockIdx.x*128, n0 = blockIdx.y*128, b = blockIdx.z;
  int tid = threadIdx.x;
  int ty = tid / 16, tx = tid % 16;
  const float* xb = xf + (size_t)b*OCN;
  float acc[8][8] = {};
  for (int c0 = 0; c0 < 513; c0 += 8){
    #pragma unroll
    for (int rr = 0; rr < 4; rr++){
      int t2 = tid + rr*256;
      int c = t2 >> 7, col = t2 & 127;
      int cc = c0 + c;
      float wv = 0.f, xv = 0.f;
      if (cc < 513){
        wv = w5t[(size_t)cc*1024 + o0 + col];
        xv = xb[(size_t)cc*NN + n0 + col];
      }
      Wsh[c][col] = wv; Xs[c][col] = xv;
    }
    __syncthreads();
    #pragma unroll
    for (int c = 0; c < 8; c++){
      float wr[8], xr[8];
      #pragma unroll
      for (int i=0;i<8;i++) wr[i] = Wsh[c][ty*8+i];
      #pragma unroll
      for (int j=0;j<8;j++) xr[j] = Xs[c][j*16+tx];
      #pragma unroll
      for (int i=0;i<8;i++)
        #pragma unroll
        for (int j=0;j<8;j++)
          acc[i][j] = fmaf(wr[i], xr[j], acc[i][j]);
    }
    __syncthreads();
  }
  #pragma unroll
  for (int i=0;i<8;i++){
    int o = o0 + ty*8 + i;
    #pragma unroll
    for (int j=0;j<8;j++){
      int n = n0 + j*16 + tx;
      y5[((size_t)b*1024 + o)*NN + n] = acc[i][j];
    }
  }
}

__global__ __launch_bounds__(256) void k_stats5_v2(const float* __restrict__ y5,
                                                   const float* __restrict__ g,
                                                   const float* __restrict__ bb,
                                                   double* __restrict__ scale,
                                                   double* __restrict__ shift){
  int o = blockIdx.x;
  __shared__ double sh1[256], sh2[256];
  double a = 0.0, q = 0.0;
  for (int bn = threadIdx.x; bn < BB*NN; bn += 256){
    int b = bn >> 11, n = bn & 2047;
    double yv = (double)y5[((size_t)b*1024 + o)*NN + n];
    a += yv; q += yv*yv;
  }
  sh1[threadIdx.x] = a; sh2[threadIdx.x] = q;
  __syncthreads();
  for (int s = 128; s > 0; s >>= 1){
    if (threadIdx.x < s){ sh1[threadIdx.x] += sh1[threadIdx.x+s]; sh2[threadIdx.x] += sh2[threadIdx.x+s]; }
    __syncthreads();
  }
  if (threadIdx.x == 0){
    double M = (double)(BB*NN);
    double mean = sh1[0]/M;
    double var  = sh2[0]/M - mean*mean;
    double sc = (double)g[o]/sqrt(var + EPSD);
    scale[o] = sc;
    shift[o] = (double)bb[o] - mean*sc;
  }
}

__global__ __launch_bounds__(256) void k_final5_v2(const float* __restrict__ y5,
                                                   const double* __restrict__ scale,
                                                   const double* __restrict__ shift,
                                                   float* __restrict__ out){
  int o = blockIdx.x, b = blockIdx.y;
  __shared__ double smx[256], ssm[256];
  double sc = scale[o], sh = shift[o];
  double mx = -INFINITY, sm = 0.0;
  const float* yrow = y5 + ((size_t)b*1024 + o)*NN;
  for (int n = threadIdx.x; n < NN; n += 256){
    double z = sc*(double)yrow[n] + sh;
    z = z > 0.0 ? z : SLOPED*z;
    mx = fmax(mx, z); sm += z;
  }
  smx[threadIdx.x] = mx; ssm[threadIdx.x] = sm;
  __syncthreads();
  for (int s = 128; s > 0; s >>= 1){
    if (threadIdx.x < s){
      smx[threadIdx.x] = fmax(smx[threadIdx.x], smx[threadIdx.x+s]);
      ssm[threadIdx.x] += ssm[threadIdx.x+s];
    }
    __syncthreads();
  }
  float vg = (float)smx[0];
  float va = (float)(ssm[0]*(1.0/NN));
  float* ob = out + (size_t)b*OCN;
  for (int n = threadIdx.x; n < NN; n += 256){
    ob[(size_t)o*NN + n] = vg;
    ob[(size_t)(1024+o)*NN + n] = va;
  }
}

extern "C" void kernel_launch(void* const* d_in, const int* in_sizes, int n_in,
                              void* d_out, int out_size, void* d_ws, size_t ws_size,
                              hipStream_t stream){
  const float* xyz = (const float*)d_in[0];
  float* out = (float*)d_out;
  float* ws  = (float*)d_ws;

  const float* Wp[5] = {(const float*)d_in[1],(const float*)d_in[4],(const float*)d_in[7],(const float*)d_in[10],(const float*)d_in[13]};
  const float* Gp[5] = {(const float*)d_in[2],(const float*)d_in[5],(const float*)d_in[8],(const float*)d_in[11],(const float*)d_in[14]};
  const float* Bp[5] = {(const float*)d_in[3],(const float*)d_in[6],(const float*)d_in[9],(const float*)d_in[12],(const float*)d_in[15]};
  int Cin[4]  = {3, 64, 64, 128};
  int Oc[4]   = {64, 64, 128, 257};
  int xoutc[4]= {2051, 2115, 2179, 2307};

  float* pd   = ws + WS_PD;
  float* ymx  = ws + WS_YMX;
  float* ymn  = ws + WS_YMN;
  float* xA   = ws + WS_XA;
  float* xB   = ws + WS_XB;
  float* u    = ws + WS_U;
  float* v    = ws + WS_V;
  int*   idx  = (int*)(ws + WS_IDX);
  float* xx   = ws + WS_XX;
  float* wtf  = ws + WS_WTF;
  float* wtd  = ws + WS_WTD;
  float* w5t  = ws + WS_W5T;
  float* y5   = ws + WS_Y5;
  double* s1d = (double*)(ws + WS_S1);
  double* s2d = (double*)(ws + WS_S2);
  double* scd = (double*)(ws + WS_SC);
  double* shd = (double*)(ws + WS_SH);

  k_prep_x0<<<cdiv(BB*NN,256), 256, 0, stream>>>(xyz, out, xA);

  for (int t = 0; t < 4; t++){
    int C = Cin[t], O = Oc[t];
    const float* xin = (t % 2 == 0) ? xA : xB;
    float* xnext = (t == 3) ? nullptr : ((t % 2 == 0) ? xB : xA);
    k_wt  <<<cdiv(C*O,256), 256, 0, stream>>>(Wp[t], wtf, wtd, C, O);
    k_xx32<<<dim3(NN/256, BB), 256, 0, stream>>>(xin, C, xx);
    hipMemsetAsync((void*)s1d, 0, 2048*sizeof(double), stream);
    int OT = (O <= 64) ? 64 : ((O <= 128) ? 128 : 256);
    for (int b = 0; b < BB; b++){
      k_pd128<<<dim3(NN/128, NN/128), 256, 0, stream>>>(xin, C, b, xx, pd);
      k_topk <<<NN/4, 256, 0, stream>>>(pd, b, idx);
    }
    k_gemm_uv<<<dim3(cdiv(O,TS), NN/TS, BB), 256, 0, stream>>>(xin, C, O, wtf, wtd, u, v);
    k_passB  <<<dim3(NN/NT, BB), 256, 0, stream>>>(u, v, idx, O, OT, ymx, ymn, s1d, s2d);
    k_stats_fin<<<cdiv(O,256), 256, 0, stream>>>(s1d, s2d, Gp[t], Bp[t], O, (double)((size_t)BB*NN*KK), scd, shd);
    k_passD<<<dim3(cdiv(O,TS), NN/TS, BB), 256, 0, stream>>>(ymx, ymn, scd, shd, O, out + (size_t)xoutc[t]*NN, xnext);
  }

  // ---- layer 5 (1x1 conv 513 -> 1024) + global pooling ----
  k_wt5   <<<cdiv(513*1024,256), 256, 0, stream>>>(Wp[4], w5t);
  k_conv5g<<<dim3(1024/128, NN/128, BB), 256, 0, stream>>>(out + (size_t)2051*NN, w5t, y5);
  k_stats5_v2<<<1024, 256, 0, stream>>>(y5, Gp[4], Bp[4], scd, shd);
  k_final5_v2<<<dim3(1024, BB), 256, 0, stream>>>(y5, scd, shd, out);
}